// Round 13
// baseline (372.192 us; speedup 1.0000x reference)
//
#include <hip/hip_runtime.h>
#include <hip/hip_fp16.h>

#define N_VOX 100000
#define KVOL 27
#define MPAIR 50000
#define CIN 64
#define COUT 64
#define TPW 4
#define NTILES 3125          // 50000 / 16, exact
#define GRIDX 196            // ceil(3125 / (4 waves * TPW))

typedef __attribute__((ext_vector_type(8))) short bf16x8;
typedef __attribute__((ext_vector_type(4))) float f32x4;
typedef __attribute__((ext_vector_type(4))) unsigned short u16x4;

__device__ inline unsigned short f2bf(float f) {  // RNE f32 -> bf16
    union { float f; unsigned u; } v; v.f = f;
    return (unsigned short)((v.u + 0x7FFFu + ((v.u >> 16) & 1u)) >> 16);
}

__global__ void spconv_zero_ws(__half2* __restrict__ ws, int n2) {
    int i = blockIdx.x * blockDim.x + threadIdx.x;
    if (i < n2) ws[i] = __float2half2_rn(0.f);
}

__global__ void spconv_x_to_bf16(const float* __restrict__ x,
                                 unsigned short* __restrict__ xbf, int n4) {
    int i = blockIdx.x * blockDim.x + threadIdx.x;
    if (i >= n4) return;
    f32x4 v = ((const f32x4*)x)[i];
    u16x4 o; o.x = f2bf(v.x); o.y = f2bf(v.y); o.z = f2bf(v.z); o.w = f2bf(v.w);
    ((u16x4*)xbf)[i] = o;
}

// out = float(ws) + bias   (also overwrites the 0xAA poison in d_out)
__global__ void spconv_finalize(const __half2* __restrict__ ws,
                                const float* __restrict__ bias,
                                float* __restrict__ out, int n2) {
    int i = blockIdx.x * blockDim.x + threadIdx.x;
    if (i >= n2) return;
    float2 v = __half22float2(ws[i]);
    int c2 = (i & (COUT / 2 - 1)) * 2;
    float2 o; o.x = v.x + bias[c2]; o.y = v.y + bias[c2 + 1];
    ((float2*)out)[i] = o;
}

// Combined: TPW=4 max-MLP gather (all loads issued before any consumer)
// + bf16 x rows (half gather lines) + pk-f16 ws scatter (half scatter stream).
__global__ __launch_bounds__(256) void spconv_mlp_f16ws(
    const unsigned short* __restrict__ xbf,
    const float* __restrict__ kern,
    const int*   __restrict__ in_map,
    const int*   __restrict__ out_map,
    __half2*     __restrict__ ws)
{
    const int lane = threadIdx.x & 63;
    const int wave = threadIdx.x >> 6;
    const int k    = blockIdx.y;
    const int g    = lane >> 4;
    const int r16  = lane & 15;
    const int p    = r16 & 1;

    const int tile0 = (blockIdx.x * 4 + wave) * TPW;
    const int base0 = k * MPAIR;

    // 1. in-row indices for all 4 tiles (coalesced; clamped, compute guarded)
    int inrow[TPW];
    #pragma unroll
    for (int t = 0; t < TPW; ++t) {
        int tl = tile0 + t; tl = tl < NTILES ? tl : NTILES - 1;
        inrow[t] = in_map[base0 + tl * 16 + r16];
    }

    // 2. issue ALL A-fragment gathers (8 outstanding b128/lane)
    bf16x8 afr[TPW][2];
    #pragma unroll
    for (int t = 0; t < TPW; ++t) {
        const unsigned short* xp = xbf + (size_t)inrow[t] * CIN + g * 8;
        afr[t][0] = *(const bf16x8*)(xp);
        afr[t][1] = *(const bf16x8*)(xp + 32);
    }

    // 3. all out-row indices (coalesced)
    int orow[TPW][4];
    #pragma unroll
    for (int t = 0; t < TPW; ++t) {
        int tl = tile0 + t; tl = tl < NTILES ? tl : NTILES - 1;
        #pragma unroll
        for (int r = 0; r < 4; ++r)
            orow[t][r] = out_map[base0 + tl * 16 + g * 4 + r];
    }

    // 4. B fragments (L2-hot)
    bf16x8 bfrag[2][4];
    {
        const float* wp = kern + (size_t)k * CIN * COUT;
        #pragma unroll
        for (int s = 0; s < 2; ++s)
            #pragma unroll
            for (int q = 0; q < 4; ++q) {
                const float* pq = wp + (s * 32 + g * 8) * COUT + q * 16 + r16;
                bf16x8 f;
                #pragma unroll
                for (int j = 0; j < 8; ++j) f[j] = (short)f2bf(pq[j * COUT]);
                bfrag[s][q] = f;
            }
    }

    // 5. drain: MFMA + pk-f16 scatter per tile
    #pragma unroll
    for (int t = 0; t < TPW; ++t) {
        if (tile0 + t < NTILES) {                 // wave-uniform guard
            f32x4 acc[4] = {{0.f,0.f,0.f,0.f},{0.f,0.f,0.f,0.f},
                            {0.f,0.f,0.f,0.f},{0.f,0.f,0.f,0.f}};
            #pragma unroll
            for (int q = 0; q < 4; ++q) {
                acc[q] = __builtin_amdgcn_mfma_f32_16x16x32_bf16(afr[t][0], bfrag[0][q], acc[q], 0, 0, 0);
                acc[q] = __builtin_amdgcn_mfma_f32_16x16x32_bf16(afr[t][1], bfrag[1][q], acc[q], 0, 0, 0);
            }
            // pk-f16 scatter (r7-verified pairing): even lanes t=0,1; odd t=2,3
            #pragma unroll
            for (int r = 0; r < 4; ++r) {
                float pv[4];
                #pragma unroll
                for (int q = 0; q < 4; ++q) pv[q] = __shfl_xor(acc[q][r], 1);
                __half2* wrow = ws + (size_t)orow[t][r] * (COUT / 2);
                #pragma unroll
                for (int q = 0; q < 2; ++q) {
                    int tt = 2 * p + q;
                    float lo = p ? pv[tt] : acc[tt][r];
                    float hi = p ? acc[tt][r] : pv[tt];
                    int col = tt * 16 + r16 - p;          // even
                    unsafeAtomicAdd(wrow + (col >> 1), __floats2half2_rn(lo, hi));
                }
            }
        }
    }
}

// ---------- fallback (ws < 25.6MB but >= 12.8MB): r9-proven path ----------
__global__ void spconv_init_bias(const float* __restrict__ bias,
                                 float* __restrict__ out, int total) {
    int i = blockIdx.x * blockDim.x + threadIdx.x;
    if (i < total) out[i] = bias[i & (COUT - 1)];
}

__global__ __launch_bounds__(256) void spconv_mfma_mlp(
    const unsigned short* __restrict__ xbf,
    const float* __restrict__ kern,
    const int*   __restrict__ in_map,
    const int*   __restrict__ out_map,
    float*       __restrict__ out)
{
    const int lane = threadIdx.x & 63;
    const int wave = threadIdx.x >> 6;
    const int k    = blockIdx.y;
    const int g    = lane >> 4;
    const int r16  = lane & 15;

    const int tile0 = (blockIdx.x * 4 + wave) * TPW;
    const int base0 = k * MPAIR;

    int inrow[TPW];
    #pragma unroll
    for (int t = 0; t < TPW; ++t) {
        int tl = tile0 + t; tl = tl < NTILES ? tl : NTILES - 1;
        inrow[t] = in_map[base0 + tl * 16 + r16];
    }
    bf16x8 afr[TPW][2];
    #pragma unroll
    for (int t = 0; t < TPW; ++t) {
        const unsigned short* xp = xbf + (size_t)inrow[t] * CIN + g * 8;
        afr[t][0] = *(const bf16x8*)(xp);
        afr[t][1] = *(const bf16x8*)(xp + 32);
    }
    int orow[TPW][4];
    #pragma unroll
    for (int t = 0; t < TPW; ++t) {
        int tl = tile0 + t; tl = tl < NTILES ? tl : NTILES - 1;
        #pragma unroll
        for (int r = 0; r < 4; ++r)
            orow[t][r] = out_map[base0 + tl * 16 + g * 4 + r];
    }
    bf16x8 bfrag[2][4];
    {
        const float* wp = kern + (size_t)k * CIN * COUT;
        #pragma unroll
        for (int s = 0; s < 2; ++s)
            #pragma unroll
            for (int q = 0; q < 4; ++q) {
                const float* pq = wp + (s * 32 + g * 8) * COUT + q * 16 + r16;
                bf16x8 f;
                #pragma unroll
                for (int j = 0; j < 8; ++j) f[j] = (short)f2bf(pq[j * COUT]);
                bfrag[s][q] = f;
            }
    }
    #pragma unroll
    for (int t = 0; t < TPW; ++t) {
        if (tile0 + t < NTILES) {
            f32x4 acc[4] = {{0.f,0.f,0.f,0.f},{0.f,0.f,0.f,0.f},
                            {0.f,0.f,0.f,0.f},{0.f,0.f,0.f,0.f}};
            #pragma unroll
            for (int q = 0; q < 4; ++q) {
                acc[q] = __builtin_amdgcn_mfma_f32_16x16x32_bf16(afr[t][0], bfrag[0][q], acc[q], 0, 0, 0);
                acc[q] = __builtin_amdgcn_mfma_f32_16x16x32_bf16(afr[t][1], bfrag[1][q], acc[q], 0, 0, 0);
            }
            #pragma unroll
            for (int r = 0; r < 4; ++r) {
                float* op = out + (size_t)orow[t][r] * COUT + r16;
                #pragma unroll
                for (int q = 0; q < 4; ++q)
                    atomicAdd(op + q * 16, acc[q][r]);
            }
        }
    }
}

extern "C" void kernel_launch(void* const* d_in, const int* in_sizes, int n_in,
                              void* d_out, int out_size, void* d_ws, size_t ws_size,
                              hipStream_t stream) {
    const float* x       = (const float*)d_in[0];
    const float* kern    = (const float*)d_in[1];
    const float* bias    = (const float*)d_in[2];
    const int*   in_map  = (const int*)d_in[3];
    const int*   out_map = (const int*)d_in[4];
    float*       out     = (float*)d_out;

    const size_t xbf_bytes = (size_t)N_VOX * CIN * sizeof(unsigned short);  // 12.8 MB
    const size_t ws_bytes  = (size_t)N_VOX * COUT * sizeof(__half);         // 12.8 MB
    int n4 = N_VOX * CIN / 4;
    int n2 = N_VOX * COUT / 2;
    dim3 grid(GRIDX, KVOL);                        // 196 x 27

    if (ws_size >= xbf_bytes + ws_bytes) {
        unsigned short* xbf = (unsigned short*)d_ws;
        __half2* ws = (__half2*)((char*)d_ws + xbf_bytes);
        spconv_x_to_bf16<<<(n4 + 255) / 256, 256, 0, stream>>>(x, xbf, n4);
        spconv_zero_ws<<<(n2 + 255) / 256, 256, 0, stream>>>(ws, n2);
        spconv_mlp_f16ws<<<grid, 256, 0, stream>>>(xbf, kern, in_map, out_map, ws);
        spconv_finalize<<<(n2 + 255) / 256, 256, 0, stream>>>(ws, bias, out, n2);
    } else {
        // proven r9-class path (requires only 12.8 MB)
        unsigned short* xbf = (unsigned short*)d_ws;
        int total = N_VOX * COUT;
        spconv_init_bias<<<(total + 255) / 256, 256, 0, stream>>>(bias, out, total);
        spconv_x_to_bf16<<<(n4 + 255) / 256, 256, 0, stream>>>(x, xbf, n4);
        spconv_mfma_mlp<<<grid, 256, 0, stream>>>(xbf, kern, in_map, out_map, out);
    }
}